// Round 7
// baseline (772.692 us; speedup 1.0000x reference)
//
#include <hip/hip_runtime.h>

typedef unsigned short u16;
typedef __attribute__((ext_vector_type(8))) short short8;
typedef __attribute__((ext_vector_type(4))) float f32x4;

#define NN 16384   // nodes
#define EE 131072  // edges
#define ERO 32768  // readout edges
#define DF 1024    // appearance dim
#define DL 300     // word2vec dim
#define DLP 320    // K-padded language dim (mult of 32)
#define DLN 384    // N-padded language B^T storage rows (3 tiles of 128)
#define DS 16      // spatial dim
#define NC 117     // classes
#define NCP 128    // padded classes

__device__ __forceinline__ float bf2f(u16 x) {
  unsigned int u = ((unsigned int)x) << 16;
  float f;
  __builtin_memcpy(&f, &u, 4);
  return f;
}
__device__ __forceinline__ u16 f2bf(float f) {
  unsigned int u;
  __builtin_memcpy(&u, &f, 4);
  u = (u + 0x7FFFu + ((u >> 16) & 1u)) >> 16;
  return (u16)u;
}
__device__ __forceinline__ float ld1(const void* p, size_t i, int f) {
  return f ? ((const float*)p)[i] : bf2f(((const u16*)p)[i]);
}
__device__ __forceinline__ void ld4(const void* p, size_t i, int f,
                                    float& x, float& y, float& z, float& w) {
  if (f) {
    float4 v = *(const float4*)((const float*)p + i);
    x = v.x; y = v.y; z = v.z; w = v.w;
  } else {
    ushort4 v = *(const ushort4*)((const u16*)p + i);
    x = bf2f(v.x); y = bf2f(v.y); z = bf2f(v.z); w = bf2f(v.w);
  }
}
__device__ __forceinline__ const void* eoff(const void* p, size_t off, int f) {
  return f ? (const void*)((const float*)p + off) : (const void*)((const u16*)p + off);
}

// dtype probe (measured: f32 on this harness; kept adaptive for safety)
__global__ void detect_kernel(const unsigned int* __restrict__ w, int* __restrict__ flag) {
  unsigned int x = w[threadIdx.x];
  int e = (x >> 7) & 0xFF;
  int ok = (e >= 97 && e <= 157);
  unsigned long long m = __ballot(ok);
  if (threadIdx.x == 0) flag[0] = (__popcll(m) >= 48) ? 0 : 1;  // 0=bf16, 1=f32
}

// contiguous cast to bf16, 8 elems/thread
__global__ void cast_bf16(const int* __restrict__ flag, const void* __restrict__ src,
                          u16* __restrict__ dst, int total8) {
  const int i = blockIdx.x * 256 + threadIdx.x;
  if (i >= total8) return;
  const int fin = flag[0];
  const size_t o = (size_t)i * 8;
  float x0, x1, x2, x3, x4, x5, x6, x7;
  ld4(src, o, fin, x0, x1, x2, x3);
  ld4(src, o + 4, fin, x4, x5, x6, x7);
  ushort4 lo, hi;
  lo.x = f2bf(x0); lo.y = f2bf(x1); lo.z = f2bf(x2); lo.w = f2bf(x3);
  hi.x = f2bf(x4); hi.y = f2bf(x5); hi.z = f2bf(x6); hi.w = f2bf(x7);
  *(ushort4*)(dst + o) = lo;
  *(ushort4*)(dst + o + 4) = hi;
}

// ---- fused weight prep: 12 transposes in one launch ----
struct TJob2 {
  const void* W; long off;
  u16* out;
  int Kr, Nr, Nstr, Kp, Np, blk0;
};
struct TPack2 { TJob2 j[12]; int nj; };

__global__ void prep_weights2(const int* __restrict__ flag, TPack2 P) {
  int b = blockIdx.x;
  int ji = 0;
  while (ji + 1 < P.nj && b >= P.j[ji + 1].blk0) ++ji;
  const TJob2 J = P.j[ji];
  const int idx = (b - J.blk0) * 256 + threadIdx.x;
  if (idx >= J.Np * J.Kp) return;
  const int n = idx / J.Kp, k = idx % J.Kp;
  float v = 0.f;
  if (k < J.Kr && n < J.Nr) v = ld1(J.W, (size_t)J.off + (size_t)k * J.Nstr + n, flag[0]);
  J.out[idx] = f2bf(v);
}

// ---- batched MFMA GEMM: C = act(A1@B1^T [+ A2@B2^T] + bias) ----
// 128x128 tile, BK=32, 4 waves (2x2 of 64x64), 16x16x32 bf16.
// FRAGMENT-ORDER LDS: segment sg (0..7) = (half = sg>>2, i = sg&3), 1 KB each;
// lane slot l holds T[half*64 + i*16 + (l&15)][k0 + (l>>4)*8 .. +7] (16 B).
// Fragment reads are then base + lane*16 (lane-linear, conflict-free b128,
// immediate segment offsets). DMA constraint (base + lane*16) satisfied by
// choosing per-lane global addresses in fragment order.
__device__ __forceinline__ void stage_frag_async(const u16* __restrict__ G, size_t rcbase,
                                                 int lda, int k0, u16* lds, int w, int lane) {
  #pragma unroll
  for (int t = 0; t < 2; ++t) {
    const int sg = (w << 1) + t;
    const int row = ((sg >> 2) << 6) + ((sg & 3) << 4) + (lane & 15);
    const u16* gp = G + (rcbase + row) * (size_t)lda + k0 + ((lane >> 4) << 3);
    __builtin_amdgcn_global_load_lds(
        (const __attribute__((address_space(1))) void*)gp,
        (__attribute__((address_space(3))) void*)(lds + sg * 512),
        16, 0, 0);
  }
}

// f32 A staged manually into the same fragment-order layout (zero-pad k>=Kreal).
// 256 threads x 16 u16: thread t -> row t>>1, quads q0=(t&1)*2, q0+1.
__device__ __forceinline__ void stage_f32_frag(const float* __restrict__ G, int row0,
                                               int lda, int k0, int Kreal,
                                               u16* lds, int tid) {
  const int row = tid >> 1;
  const int q0 = (tid & 1) << 1;
  const int sg = ((row >> 6) << 2) + ((row >> 4) & 3);
  const int r15 = row & 15;
  const float* gr = G + (size_t)(row0 + row) * lda;
  #pragma unroll
  for (int qq = 0; qq < 2; ++qq) {
    const int q = q0 + qq;
    const int kk = k0 + (q << 3);
    float4 v0 = make_float4(0.f, 0.f, 0.f, 0.f);
    float4 v1 = make_float4(0.f, 0.f, 0.f, 0.f);
    if (kk < Kreal) {
      v0 = *(const float4*)(gr + kk);
      if (kk + 4 < Kreal) v1 = *(const float4*)(gr + kk + 4);
    }
    u16* dst = lds + sg * 512 + (((q << 4) + r15) << 3);
    ushort4 a, b;
    a.x = f2bf(v0.x); a.y = f2bf(v0.y); a.z = f2bf(v0.z); a.w = f2bf(v0.w);
    b.x = f2bf(v1.x); b.y = f2bf(v1.y); b.z = f2bf(v1.z); b.w = f2bf(v1.w);
    *(ushort4*)dst = a;
    *(ushort4*)(dst + 4) = b;
  }
}

__device__ __forceinline__ void kloop(int am, const void* __restrict__ A, int lda,
                                      int Kreal, int Kpad, const u16* __restrict__ B,
                                      u16* As, u16* Bs, f32x4 (&acc)[4][4],
                                      int row0, int col0,
                                      int tid, int lane, int w, int wm, int wn) {
  const int lo8 = lane << 3;  // lane slot in u16 units
  for (int k0 = 0; k0 < Kpad; k0 += 32) {
    if (am == 0) stage_frag_async((const u16*)A, (size_t)row0, lda, k0, As, w, lane);
    else         stage_f32_frag((const float*)A, row0, lda, k0, Kreal, As, tid);
    stage_frag_async(B, (size_t)col0, Kpad, k0, Bs, w, lane);
    __syncthreads();
    short8 af[4], bfr[4];
    #pragma unroll
    for (int i = 0; i < 4; ++i)
      af[i] = *(const short8*)(As + (((wm << 2) + i) << 9) + lo8);
    #pragma unroll
    for (int j = 0; j < 4; ++j)
      bfr[j] = *(const short8*)(Bs + (((wn << 2) + j) << 9) + lo8);
    #pragma unroll
    for (int i = 0; i < 4; ++i)
      #pragma unroll
      for (int j = 0; j < 4; ++j)
        acc[i][j] = __builtin_amdgcn_mfma_f32_16x16x32_bf16(af[i], bfr[j], acc[i][j], 0, 0, 0);
    __syncthreads();
  }
}

struct GJob {
  const void* A1; const u16* B1;
  const void* A2; const u16* B2;
  const void* bias; void* C;
  int lda1, K1real, K1pad, am1;
  int lda2, K2real, K2pad, am2;   // am2 = -1 -> no second pair
  int inBias, ldc, Nreal, Npad, relu, cf32;
  int gx, gy, blk0;               // tile grid; gy % 8 == 0
};
struct GPack { GJob j[2]; int nj; };

__global__ __launch_bounds__(256) void mfma_jobs(const int* __restrict__ flag, GPack P) {
  const int b = blockIdx.x;
  int ji = 0;
  if (P.nj > 1 && b >= P.j[1].blk0) ji = 1;
  const GJob J = P.j[ji];
  const int t = b - J.blk0;
  // XCD-aware swizzle: each XCD owns a row band, sweeps columns within a row tile
  const int xcd = t & 7, s = t >> 3;
  const int row_t = xcd * (J.gy >> 3) + s / J.gx;
  const int col_t = s % J.gx;
  const int row0 = row_t << 7;
  const int col0 = col_t << 7;

  __shared__ __attribute__((aligned(16))) u16 As[128 * 32];
  __shared__ __attribute__((aligned(16))) u16 Bs[128 * 32];
  const int tid = threadIdx.x;
  const int lane = tid & 63;
  const int w = tid >> 6;
  const int wm = w >> 1, wn = w & 1;
  const int ml = lane & 15, q = lane >> 4;

  f32x4 acc[4][4];
  #pragma unroll
  for (int i = 0; i < 4; ++i)
    #pragma unroll
    for (int j = 0; j < 4; ++j) {
      f32x4 z = {0.f, 0.f, 0.f, 0.f};
      acc[i][j] = z;
    }

  kloop(J.am1, J.A1, J.lda1, J.K1real, J.K1pad, J.B1, As, Bs, acc,
        row0, col0, tid, lane, w, wm, wn);
  if (J.am2 >= 0)
    kloop(J.am2, J.A2, J.lda2, J.K2real, J.K2pad, J.B2, As, Bs, acc,
          row0, col0, tid, lane, w, wm, wn);

  const int fin = flag[0];
  // C/D layout (m89-verified): col = lane&15, row = (lane>>4)*4 + reg
  #pragma unroll
  for (int j = 0; j < 4; ++j) {
    const int col = col0 + (wn << 6) + (j << 4) + ml;
    if (col >= J.Npad) continue;
    float bv = 0.f;
    if (J.bias && col < J.Nreal) bv = ld1(J.bias, col, J.inBias ? fin : 0);
    #pragma unroll
    for (int i = 0; i < 4; ++i) {
      #pragma unroll
      for (int r = 0; r < 4; ++r) {
        const int row = row0 + (wm << 6) + (i << 4) + (q << 2) + r;
        float v = 0.f;
        if (col < J.Nreal) {
          v = acc[i][j][r] + bv;
          if (J.relu) v = fmaxf(v, 0.f);
        }
        if (J.cf32) {
          ((float*)J.C)[(size_t)row * J.ldc + col] = v;
        } else {
          // pack adjacent cols (lane l, l^1) into one u32 store by even lanes
          unsigned mine = f2bf(v);
          unsigned other = (unsigned)__shfl_xor((int)mine, 1, 64);
          if (!(lane & 1)) {
            unsigned word = mine | (other << 16);
            *(unsigned*)((u16*)J.C + (size_t)row * J.ldc + (col & ~1)) = word;
          }
        }
      }
    }
  }
}

// --- CSR build ---
__global__ void cnt_kernel(const int* __restrict__ edst, int* __restrict__ cnt) {
  const int i = blockIdx.x * 256 + threadIdx.x;
  if (i < EE) atomicAdd(&cnt[edst[i]], 1);
}

__global__ __launch_bounds__(1024) void scan_kernel(const int* __restrict__ cnt,
                                                    int* __restrict__ offs,
                                                    int* __restrict__ woffs) {
  __shared__ int part[1024];
  const int t = threadIdx.x;
  const int base = t * 16;
  int loc[16];
  int s = 0;
  #pragma unroll
  for (int i = 0; i < 16; ++i) { loc[i] = s; s += cnt[base + i]; }
  part[t] = s;
  __syncthreads();
  for (int off = 1; off < 1024; off <<= 1) {
    int v = (t >= off) ? part[t - off] : 0;
    __syncthreads();
    part[t] += v;
    __syncthreads();
  }
  const int chunk_excl = (t == 0) ? 0 : part[t - 1];
  #pragma unroll
  for (int i = 0; i < 16; ++i) {
    int o = chunk_excl + loc[i];
    offs[base + i] = o;
    woffs[base + i] = o;
  }
  if (t == 1023) offs[NN] = part[1023];
}

__global__ void scatter_kernel(const int* __restrict__ esrc, const int* __restrict__ edst,
                               int* __restrict__ woffs,
                               int* __restrict__ order, int* __restrict__ srcs) {
  const int e = blockIdx.x * 256 + threadIdx.x;
  if (e < EE) {
    const int d = edst[e];
    const int pos = atomicAdd(&woffs[d], 1);
    order[pos] = e;
    srcs[pos] = esrc[e];
  }
}

// appearance aggregation: one block per dst node; P12 interleaved [n][2048] (P1|P2).
// Edge loop unrolled x4 (16 independent FMA chains).
__global__ __launch_bounds__(256) void app_agg(
    const int* __restrict__ flag,
    const u16* __restrict__ P12, const void* __restrict__ s_f,
    const void* __restrict__ W_eb, const void* __restrict__ b_e,
    const int* __restrict__ offs, const int* __restrict__ order,
    const int* __restrict__ srcs, u16* __restrict__ aggn)
{
  const int fin = flag[0];
  const int n = blockIdx.x;
  const int tid = threadIdx.x;
  const int c4 = tid << 2;
  const void* W_es = eoff(W_eb, (size_t)2 * DF * DF, fin);

  float wx[16], wy[16], wz[16], ww[16];
  #pragma unroll
  for (int k = 0; k < 16; ++k)
    ld4(W_es, (size_t)k * DF + c4, fin, wx[k], wy[k], wz[k], ww[k]);

  float be0, be1, be2, be3;
  ld4(b_e, c4, fin, be0, be1, be2, be3);
  const ushort4 p2 = *(const ushort4*)(P12 + (size_t)n * 2048 + 1024 + c4);
  const float base0 = bf2f(p2.x) + be0;
  const float base1 = bf2f(p2.y) + be1;
  const float base2 = bf2f(p2.z) + be2;
  const float base3 = bf2f(p2.w) + be3;

  const int beg = offs[n], end = offs[n + 1];
  float a0 = 0.f, a1 = 0.f, a2 = 0.f, a3 = 0.f;
  int j = beg;
  for (; j + 4 <= end; j += 4) {
    int ee[4], ss[4];
    #pragma unroll
    for (int m = 0; m < 4; ++m) { ee[m] = order[j + m]; ss[m] = srcs[j + m]; }
    float u0[4], u1[4], u2[4], u3[4], sfv[4][16];
    #pragma unroll
    for (int m = 0; m < 4; ++m) {
      #pragma unroll
      for (int k = 0; k < 16; k += 4)
        ld4(s_f, (size_t)ee[m] * DS + k, fin,
            sfv[m][k], sfv[m][k + 1], sfv[m][k + 2], sfv[m][k + 3]);
      const ushort4 pm = *(const ushort4*)(P12 + (size_t)ss[m] * 2048 + c4);
      u0[m] = bf2f(pm.x) + base0;
      u1[m] = bf2f(pm.y) + base1;
      u2[m] = bf2f(pm.z) + base2;
      u3[m] = bf2f(pm.w) + base3;
    }
    #pragma unroll
    for (int k = 0; k < 16; ++k)
      #pragma unroll
      for (int m = 0; m < 4; ++m) {
        u0[m] = fmaf(sfv[m][k], wx[k], u0[m]);
        u1[m] = fmaf(sfv[m][k], wy[k], u1[m]);
        u2[m] = fmaf(sfv[m][k], wz[k], u2[m]);
        u3[m] = fmaf(sfv[m][k], ww[k], u3[m]);
      }
    #pragma unroll
    for (int m = 0; m < 4; ++m) {
      a0 += fmaxf(u0[m], 0.f); a1 += fmaxf(u1[m], 0.f);
      a2 += fmaxf(u2[m], 0.f); a3 += fmaxf(u3[m], 0.f);
    }
  }
  for (; j < end; ++j) {
    const int e = order[j], s = srcs[j];
    float sf[16];
    #pragma unroll
    for (int k = 0; k < 16; k += 4)
      ld4(s_f, (size_t)e * DS + k, fin, sf[k], sf[k + 1], sf[k + 2], sf[k + 3]);
    const ushort4 p1 = *(const ushort4*)(P12 + (size_t)s * 2048 + c4);
    float v0 = bf2f(p1.x) + base0;
    float v1 = bf2f(p1.y) + base1;
    float v2 = bf2f(p1.z) + base2;
    float v3 = bf2f(p1.w) + base3;
    #pragma unroll
    for (int k = 0; k < 16; ++k) {
      v0 = fmaf(sf[k], wx[k], v0);
      v1 = fmaf(sf[k], wy[k], v1);
      v2 = fmaf(sf[k], wz[k], v2);
      v3 = fmaf(sf[k], ww[k], v3);
    }
    a0 += fmaxf(v0, 0.f); a1 += fmaxf(v1, 0.f);
    a2 += fmaxf(v2, 0.f); a3 += fmaxf(v3, 0.f);
  }
  const float inv = 1.f / fmaxf((float)(end - beg), 1.f);
  ushort4 o;
  o.x = f2bf(a0 * inv); o.y = f2bf(a1 * inv);
  o.z = f2bf(a2 * inv); o.w = f2bf(a3 * inv);
  *(ushort4*)(aggn + (size_t)n * DF + c4) = o;
}

// language aggregation: Q12 interleaved [n][768] (Q1 @0 | Q2 @384); out [NN][DLP] zero-pad
__global__ __launch_bounds__(320) void lang_agg(
    const int* __restrict__ flag,
    const u16* __restrict__ Q12, const void* __restrict__ b_el,
    const int* __restrict__ offs, const int* __restrict__ srcs,
    u16* __restrict__ aggln)
{
  const int fin = flag[0];
  const int n = blockIdx.x;
  const int c = threadIdx.x;
  if (c >= DL) { aggln[(size_t)n * DLP + c] = 0; return; }
  const float base = bf2f(Q12[(size_t)n * 768 + 384 + c]) + ld1(b_el, c, fin);
  const int beg = offs[n], end = offs[n + 1];
  float s0 = 0.f, s1 = 0.f, s2 = 0.f, s3 = 0.f;
  int j = beg;
  for (; j + 4 <= end; j += 4) {
    s0 += fmaxf(bf2f(Q12[(size_t)srcs[j] * 768 + c]) + base, 0.f);
    s1 += fmaxf(bf2f(Q12[(size_t)srcs[j + 1] * 768 + c]) + base, 0.f);
    s2 += fmaxf(bf2f(Q12[(size_t)srcs[j + 2] * 768 + c]) + base, 0.f);
    s3 += fmaxf(bf2f(Q12[(size_t)srcs[j + 3] * 768 + c]) + base, 0.f);
  }
  for (; j < end; ++j) s0 += fmaxf(bf2f(Q12[(size_t)srcs[j] * 768 + c]) + base, 0.f);
  const float a = (s0 + s1) + (s2 + s3);
  aggln[(size_t)n * DLP + c] = f2bf(a / fmaxf((float)(end - beg), 1.f));
}

// pred[e] = RdRs[dst,0:117] + RdRs[src,128:245] + s_f_ro[e]@Wp_s + b_p
__global__ __launch_bounds__(256) void readout_kernel(
    const int* __restrict__ flag,
    const float* __restrict__ RdRs,
    const void* __restrict__ s_f_ro,
    const void* __restrict__ W_pb, size_t offWps,
    const void* __restrict__ b_p,
    const int* __restrict__ rsrc, const int* __restrict__ rdst, void* __restrict__ out)
{
  const int fin = flag[0];
  __shared__ float wps[16 * NC];
  const void* Wp_s = eoff(W_pb, offWps, fin);
  const int tid = threadIdx.x;
  for (int i = tid; i < 16 * NC; i += 256) wps[i] = ld1(Wp_s, i, fin);
  __syncthreads();
  const int slot = tid >> 7;        // 0 or 1
  const int c = tid & 127;
  const float bp = (c < NC) ? ld1(b_p, c, fin) : 0.f;

  const int e0 = (blockIdx.x << 3) + slot;
  #pragma unroll
  for (int ee = 0; ee < 8; ee += 2) {
    const int e = e0 + ee;
    const int s = rsrc[e];
    const int d = rdst[e];
    if (c < NC) {
      float acc = RdRs[(size_t)d * 256 + c] + RdRs[(size_t)s * 256 + 128 + c] + bp;
      #pragma unroll
      for (int k = 0; k < 16; ++k)
        acc = fmaf(ld1(s_f_ro, (size_t)e * DS + k, fin), wps[k * NC + c], acc);
      if (fin) ((float*)out)[(size_t)e * NC + c] = acc;
      else     ((u16*)out)[(size_t)e * NC + c] = f2bf(acc);
    }
  }
}

extern "C" void kernel_launch(void* const* d_in, const int* in_sizes, int n_in,
                              void* d_out, int out_size, void* d_ws, size_t ws_size,
                              hipStream_t stream)
{
  const void* feat  = d_in[0];
  const void* w2v   = d_in[1];
  const void* s_f   = d_in[2];
  const void* s_fro = d_in[3];
  const void* W_e   = d_in[4];
  const void* b_e   = d_in[5];
  const void* W_el  = d_in[6];
  const void* b_el  = d_in[7];
  const void* W_nu  = d_in[8];
  const void* b_nu  = d_in[9];
  const void* W_nul = d_in[10];
  const void* b_nul = d_in[11];
  const void* W_p   = d_in[12];
  const void* b_p   = d_in[13];
  const int* esrc  = (const int*)d_in[14];
  const int* edst  = (const int*)d_in[15];
  const int* rsrc  = (const int*)d_in[16];
  const int* rdst  = (const int*)d_in[17];

  // ---- workspace layout: ~172.8 MB (R4-proven envelope) ----
  char* p = (char*)d_ws;
  int* flag  = (int*)p; p += 256;
  int* cnt   = (int*)p; p += (size_t)NN * 4;
  int* offs  = (int*)p; p += (size_t)(NN + 64) * 4;
  int* woffs = (int*)p; p += (size_t)NN * 4;
  int* order = (int*)p; p += (size_t)EE * 4;
  int* srcs  = (int*)p; p += (size_t)EE * 4;
  u16* featB  = (u16*)p; p += (size_t)NN * DF * 2;        // 32 MB bf16 feat
  u16* We12T  = (u16*)p; p += (size_t)2 * DF * DF * 2;    // [2048][1024]
  u16* Wnu1T  = (u16*)p; p += (size_t)DF * DF * 2;
  u16* Wnu2T  = (u16*)p; p += (size_t)DF * DF * 2;
  u16* Wel12T = (u16*)p; p += (size_t)2 * DLN * DLP * 2;  // [768][320]
  u16* Wnul1T = (u16*)p; p += (size_t)DLN * DLP * 2;
  u16* Wnul2T = (u16*)p; p += (size_t)DLN * DLP * 2;
  u16* WpFT2  = (u16*)p; p += (size_t)2 * NCP * DF * 2;   // [256][1024] (Rd-F | Rs-F)
  u16* WpLT2  = (u16*)p; p += (size_t)2 * NCP * DLP * 2;  // [256][320]  (Rd-L | Rs-L)
  u16* P12   = (u16*)p; p += (size_t)NN * 2048 * 2;       // 64 MB; later newf+newl
  u16* Q12   = (u16*)p; p += (size_t)NN * 768 * 2;        // 24 MB; later RdRs (16 MB f32)
  u16* aggln = (u16*)p; p += (size_t)NN * DLP * 2;        // 10 MB
  u16* aggn  = (u16*)p; p += (size_t)NN * DF * 2;         // 32 MB
  // aliases (stream-ordered: P12 dead after app_agg; Q12 dead after lang_agg)
  u16* newf = P12;
  u16* newl = P12 + (size_t)NN * DF;
  float* RdRs = (float*)Q12;

  detect_kernel<<<1, 64, 0, stream>>>((const unsigned int*)feat, flag);
  hipMemsetAsync(cnt, 0, (size_t)NN * 4, stream);
  cast_bf16<<<(NN * DF / 8 + 255) / 256, 256, 0, stream>>>(flag, feat, featB, NN * DF / 8);

  // ---- fused weight prep (12 transposes, one launch) ----
  TPack2 tp{};
  int tb = 0, tn = 0;
  auto T = [&](const void* W, long off, int Kr, int Nr, int Nstr, u16* out, int Kp, int Np) {
    tp.j[tn] = TJob2{W, off, out, Kr, Nr, Nstr, Kp, Np, tb};
    tb += (Np * Kp + 255) / 256;
    ++tn;
  };
  T(W_e,   0,                   DF, DF, DF, We12T,                     DF, DF);
  T(W_e,   (long)DF * DF,       DF, DF, DF, We12T + (size_t)DF * DF,   DF, DF);
  T(W_nu,  0,                   DF, DF, DF, Wnu1T, DF, DF);
  T(W_nu,  (long)DF * DF,       DF, DF, DF, Wnu2T, DF, DF);
  T(W_el,  0,                   DL, DL, DL, Wel12T,                     DLP, DLN);
  T(W_el,  (long)DL * DL,       DL, DL, DL, Wel12T + (size_t)DLN * DLP, DLP, DLN);
  T(W_nul, 0,                   DL, DL, DL, Wnul1T, DLP, DLN);
  T(W_nul, (long)DL * DL,       DL, DL, DL, Wnul2T, DLP, DLN);
  T(W_p,   0,                                DF, NC, NC, WpFT2,                     DF,  NCP);
  T(W_p,   (long)(DF + DL + DS + DL) * NC,   DF, NC, NC, WpFT2 + (size_t)NCP * DF,  DF,  NCP);
  T(W_p,   (long)DF * NC,                    DL, NC, NC, WpLT2,                     DLP, NCP);
  T(W_p,   (long)(DF + DL + DS) * NC,        DL, NC, NC, WpLT2 + (size_t)NCP * DLP, DLP, NCP);
  tp.nj = tn;
  prep_weights2<<<tb, 256, 0, stream>>>(flag, tp);

  // ---- CSR build ----
  cnt_kernel<<<EE / 256, 256, 0, stream>>>(edst, cnt);
  scan_kernel<<<1, 1024, 0, stream>>>(cnt, offs, woffs);
  scatter_kernel<<<EE / 256, 256, 0, stream>>>(esrc, edst, woffs, order, srcs);

  // ---- GEMM phase 1: P12 (featB @ We12T^T) + Q12 (w2v @ Wel12T^T) ----
  {
    GPack g{};
    g.j[0] = GJob{featB, We12T, nullptr, nullptr, nullptr, P12,
                  DF, DF, DF, 0,    0, 0, 0, -1,
                  0, 2048, 2048, 2048, 0, 0,  16, 128, 0};
    g.j[1] = GJob{w2v, Wel12T, nullptr, nullptr, nullptr, Q12,
                  DL, DL, DLP, 1,   0, 0, 0, -1,
                  0, 768, 768, 768, 0, 0,    6, 128, 2048};
    g.nj = 2;
    mfma_jobs<<<2048 + 768, 256, 0, stream>>>(flag, g);
  }

  // ---- aggregations (CSR, no atomics) ----
  lang_agg<<<NN, DLP, 0, stream>>>(flag, Q12, b_el, offs, srcs, aggln);
  app_agg<<<NN, 256, 0, stream>>>(flag, P12, s_f, W_e, b_e, offs, order, srcs, aggn);

  // ---- GEMM phase 2: node updates (newf/newl alias P12 - dead after app_agg) ----
  {
    GPack g{};
    g.j[0] = GJob{featB, Wnu1T, aggn, Wnu2T, b_nu, newf,
                  DF, DF, DF, 0,    DF, DF, DF, 0,
                  1, DF, DF, DF, 1, 0,       8, 128, 0};
    g.j[1] = GJob{w2v, Wnul1T, aggln, Wnul2T, b_nul, newl,
                  DL, DL, DLP, 1,   DLP, DLP, DLP, 0,
                  1, DLP, DL, DLP, 1, 0,     3, 128, 1024};
    g.nj = 2;
    mfma_jobs<<<1024 + 384, 256, 0, stream>>>(flag, g);
  }

  // ---- GEMM phase 3: fused readout projections (f32, [NN][256]: Rd | Rs) ----
  {
    GPack g{};
    g.j[0] = GJob{newf, WpFT2, newl, WpLT2, nullptr, RdRs,
                  DF, DF, DF, 0,    DLP, DLP, DLP, 0,
                  0, 256, 256, 256, 0, 1,    2, 128, 0};
    g.nj = 1;
    mfma_jobs<<<256, 256, 0, stream>>>(flag, g);
  }

  readout_kernel<<<ERO / 8, 256, 0, stream>>>(flag, RdRs, s_fro,
                                              W_p, (size_t)(DF + DL) * NC, b_p,
                                              rsrc, rdst, d_out);
}